// Round 2
// baseline (415.687 us; speedup 1.0000x reference)
//
#include <hip/hip_runtime.h>
#include <math.h>

// RoPE over x[4,32,4096,128] fp32, positions = token_positions[4096] (int32).
// Pairwise rotation on (even, odd) feature pairs:
//   out[2i]   = cos(a)*x[2i] - sin(a)*x[2i+1]
//   out[2i+1] = sin(a)*x[2i] + cos(a)*x[2i+1],  a = pos * theta^(-2i/128)
//
// Memory-bound: 512 MiB traffic -> ~85 us floor at 6.3 TB/s.
// One thread per float4 (2 pairs): coalesced 16B loads/stores.

#define THETA_LOG2_OVER_HALF 0.20762050593046013f   // log2(10000)/64
#define FREQ_STEP 0.8659643233600653f               // 10000^(-1/64)

__global__ __launch_bounds__(256) void rope_f32_kernel(
    const float4* __restrict__ x,
    const int* __restrict__ token_positions,
    float4* __restrict__ out,
    int n4)
{
    int t = blockIdx.x * blockDim.x + threadIdx.x;
    if (t >= n4) return;

    // 128 floats per row = 32 float4 per row; 4096 rows per (b,h) slice.
    int s  = (t >> 5) & 4095;     // sequence index within the slice
    int i0 = (t & 31) * 2;        // first pair index handled by this float4

    float p = (float)token_positions[s];

    // inv_freq(i0) and inv_freq(i0+1) = inv_freq(i0) * 10000^(-1/64)
    float f0 = exp2f(-THETA_LOG2_OVER_HALF * (float)i0);
    float f1 = f0 * FREQ_STEP;

    float a0 = p * f0;
    float a1 = p * f1;

    float s0 = __sinf(a0), c0 = __cosf(a0);
    float s1 = __sinf(a1), c1 = __cosf(a1);

    float4 v = x[t];
    float4 r;
    r.x = c0 * v.x - s0 * v.y;
    r.y = s0 * v.x + c0 * v.y;
    r.z = c1 * v.z - s1 * v.w;
    r.w = s1 * v.z + c1 * v.w;
    out[t] = r;
}

extern "C" void kernel_launch(void* const* d_in, const int* in_sizes, int n_in,
                              void* d_out, int out_size, void* d_ws, size_t ws_size,
                              hipStream_t stream) {
    const float* x = (const float*)d_in[0];
    const int* token_positions = (const int*)d_in[1];
    float* out = (float*)d_out;

    int n4 = out_size / 4;                 // 16,777,216 float4s
    int block = 256;
    int grid = (n4 + block - 1) / block;   // 65,536 blocks

    rope_f32_kernel<<<grid, block, 0, stream>>>(
        (const float4*)x, token_positions, (float4*)out, n4);
}